// Round 2
// baseline (626.394 us; speedup 1.0000x reference)
//
#include <hip/hip_runtime.h>
#include <hip/hip_bf16.h>

#define S_LEN 2048
#define NH 8
#define HD 64
#define CH 512
#define NEG_BIG (-3.0e38f)

typedef __bf16 bf16;
typedef bf16 bf16x8 __attribute__((ext_vector_type(8)));
typedef bf16 bf16x4 __attribute__((ext_vector_type(4)));
typedef float floatx4 __attribute__((ext_vector_type(4)));

// ---------------------------------------------------------------------------
// Mask dtype detection: bool mask may arrive as int32 / uint8 / float32.
// int32 0/1  -> bytes at off%4!=0 are all zero
// uint8 0/1  -> bytes at off%4==1 nonzero with prob ~1 over 1K samples
// float 0/1  -> bytes at off%4==2,3 nonzero (0x80,0x3F), off%4==1 zero
// flag: 0=int32, 1=uint8, 2=float32
// ---------------------------------------------------------------------------
__global__ void detect_mask_kernel(const unsigned char* __restrict__ mb,
                                   int* __restrict__ flag_out) {
    __shared__ int s1, s3;
    if (threadIdx.x == 0) { s1 = 0; s3 = 0; }
    __syncthreads();
    int any1 = 0, any3 = 0;
    int base = threadIdx.x * 16;
    for (int i = base; i < base + 16; ++i) {
        unsigned char bch = mb[i];
        int m = i & 3;
        if (bch != 0) {
            if (m == 1) any1 = 1;
            if (m == 2 || m == 3) any3 = 1;
        }
    }
    if (any1) atomicOr(&s1, 1);
    if (any3) atomicOr(&s3, 1);
    __syncthreads();
    if (threadIdx.x == 0) {
        int f = 0;
        if (s1) f = 1;
        else if (s3) f = 2;
        *flag_out = f;
    }
}

// ---------------------------------------------------------------------------
// fp32 GEMM: OUT[row, col] = (sum_c IN[row,c] * W[c,col] + BI[col]) * scale
// M=4096, N=512, K=512. 128x128 tile, BK=16, 256 threads, 8x8 micro-tile.
// mode 0: OUT in [b,h,s,d]  (q/k projections)
// mode 1: OUT in [b,h,d,s]  (v projection, pre-transposed for attention)
// mode 2: OUT flat [row, col]
// ---------------------------------------------------------------------------
__device__ __forceinline__ void gemm_tile(
    float (* __restrict__ AsT)[132], float (* __restrict__ Bs)[132],
    const float* __restrict__ IN, const float* __restrict__ W,
    const float* __restrict__ BI, float* __restrict__ OUT,
    float scale, int mode)
{
    const int t  = threadIdx.x;
    const int m0 = blockIdx.y * 128;
    const int n0 = blockIdx.x * 128;
    const int r0 = (t >> 4) << 3;   // 0..120
    const int c0 = (t & 15) << 2;   // 0..60 ; cols = {c0..c0+3} U {c0+64..c0+67}

    float acc[8][8];
#pragma unroll
    for (int i = 0; i < 8; ++i)
#pragma unroll
        for (int j = 0; j < 8; ++j) acc[i][j] = 0.f;

    for (int k0 = 0; k0 < CH; k0 += 16) {
        __syncthreads();
        // stage A (transposed into AsT[k][m]) : 128 rows x 16 k
#pragma unroll
        for (int i = 0; i < 2; ++i) {
            int fl = t + 256 * i;
            int ml = fl >> 2;
            int k4 = (fl & 3) << 2;
            float4 va = *(const float4*)(IN + (size_t)(m0 + ml) * CH + k0 + k4);
            AsT[k4 + 0][ml] = va.x;
            AsT[k4 + 1][ml] = va.y;
            AsT[k4 + 2][ml] = va.z;
            AsT[k4 + 3][ml] = va.w;
        }
        // stage B (direct) : 16 k x 128 cols
#pragma unroll
        for (int i = 0; i < 2; ++i) {
            int fl = t + 256 * i;
            int kr = fl >> 5;
            int n4 = (fl & 31) << 2;
            *(float4*)&Bs[kr][n4] =
                *(const float4*)(W + (size_t)(k0 + kr) * CH + n0 + n4);
        }
        __syncthreads();
#pragma unroll
        for (int k = 0; k < 16; ++k) {
            float4 A0 = *(const float4*)&AsT[k][r0];
            float4 A1 = *(const float4*)&AsT[k][r0 + 4];
            float4 B0 = *(const float4*)&Bs[k][c0];
            float4 B1 = *(const float4*)&Bs[k][c0 + 64];
            float av[8] = {A0.x, A0.y, A0.z, A0.w, A1.x, A1.y, A1.z, A1.w};
            float bv[8] = {B0.x, B0.y, B0.z, B0.w, B1.x, B1.y, B1.z, B1.w};
#pragma unroll
            for (int i = 0; i < 8; ++i)
#pragma unroll
                for (int j = 0; j < 8; ++j)
                    acc[i][j] = fmaf(av[i], bv[j], acc[i][j]);
        }
    }

    float bj[8];
#pragma unroll
    for (int j = 0; j < 8; ++j) {
        int col = n0 + c0 + ((j >> 2) << 6) + (j & 3);
        bj[j] = BI[col];
    }
#pragma unroll
    for (int i = 0; i < 8; ++i) {
        int row = m0 + r0 + i;
        int bb = row >> 11;          // row / 2048
        int ss = row & (S_LEN - 1);
#pragma unroll
        for (int j = 0; j < 8; ++j) {
            int col = n0 + c0 + ((j >> 2) << 6) + (j & 3);
            float v = (acc[i][j] + bj[j]) * scale;
            if (mode == 0) {
                int hh = col >> 6, dd = col & 63;
                OUT[(((size_t)bb * NH + hh) * S_LEN + ss) * HD + dd] = v;
            } else if (mode == 1) {
                int hh = col >> 6, dd = col & 63;
                OUT[(((size_t)bb * NH + hh) * HD + dd) * S_LEN + ss] = v;
            } else {
                OUT[(size_t)row * CH + col] = v;
            }
        }
    }
}

__global__ __launch_bounds__(256) void qkv_gemm_kernel(
    const float* __restrict__ q_in, const float* __restrict__ k_in,
    const float* __restrict__ v_in,
    const float* __restrict__ Wq, const float* __restrict__ bq,
    const float* __restrict__ Wk, const float* __restrict__ bk,
    const float* __restrict__ Wv, const float* __restrict__ bv,
    float* __restrict__ qp, float* __restrict__ kp, float* __restrict__ vpT)
{
    __shared__ float AsT[16][132];
    __shared__ float Bs[16][132];
    int z = blockIdx.z;
    if (z == 0)      gemm_tile(AsT, Bs, q_in, Wq, bq, qp, 0.125f, 0);
    else if (z == 1) gemm_tile(AsT, Bs, k_in, Wk, bk, kp, 1.0f, 0);
    else             gemm_tile(AsT, Bs, v_in, Wv, bv, vpT, 1.0f, 1);
}

__global__ __launch_bounds__(256) void out_gemm_kernel(
    const float* __restrict__ ctx, const float* __restrict__ Wo,
    const float* __restrict__ bo, float* __restrict__ out)
{
    __shared__ float AsT[16][132];
    __shared__ float Bs[16][132];
    gemm_tile(AsT, Bs, ctx, Wo, bo, out, 1.0f, 2);
}

// ---------------------------------------------------------------------------
// Flash attention, bf16 MFMA (16x16x32), fp32 online softmax in registers.
// Block: 256 threads = 4 waves; each wave owns a 16-row q strip of a 64-row
// q tile. K-tiles of 64 keys. Q frags in registers; Kbf/VsT/Pbf in LDS
// (stride 72 shorts = 144B rows -> all ds_read_b128 16B-aligned).
// Fragment maps (gfx950, HW-verified in guide):
//   A[m=lane&15][k=quad*8+j],  B[k=quad*8+j][n=lane&15],
//   C/D: col=lane&15, row=quad*4+reg.
// ---------------------------------------------------------------------------
__global__ __launch_bounds__(256) void attn_kernel(
    const float* __restrict__ qp, const float* __restrict__ kp,
    const float* __restrict__ vpT, const float* __restrict__ bias,
    const void* __restrict__ mask, const int* __restrict__ flagp,
    float* __restrict__ ctxb)
{
    __shared__ __attribute__((aligned(16))) bf16 Kbf[64 * 72];
    __shared__ __attribute__((aligned(16))) bf16 VsT[64 * 72];
    __shared__ __attribute__((aligned(16))) bf16 Pbf[64 * 72];

    const int t    = threadIdx.x;
    const int w    = t >> 6;
    const int lane = t & 63;
    const int m    = lane & 15;
    const int quad = lane >> 4;
    const int q0   = blockIdx.x * 64;
    const int h    = blockIdx.y;
    const int b    = blockIdx.z;
    const int bh   = b * NH + h;
    const int flag = *flagp;

    // Q fragments: rows q0 + 16*w + m, prescaled by 1/8 in projection
    bf16x8 qf[2];
    {
        const float* qrow =
            qp + ((size_t)bh * S_LEN + q0 + 16 * w + m) * HD + 8 * quad;
#pragma unroll
        for (int c = 0; c < 2; ++c) {
            float4 f0 = *(const float4*)(qrow + 32 * c);
            float4 f1 = *(const float4*)(qrow + 32 * c + 4);
            bf16x8 v;
            v[0] = (bf16)f0.x; v[1] = (bf16)f0.y; v[2] = (bf16)f0.z; v[3] = (bf16)f0.w;
            v[4] = (bf16)f1.x; v[5] = (bf16)f1.y; v[6] = (bf16)f1.z; v[7] = (bf16)f1.w;
            qf[c] = v;
        }
    }

    floatx4 ctx[4];
    float mrow[4], lrow[4];
#pragma unroll
    for (int tt = 0; tt < 4; ++tt) { ctx[tt][0]=0.f; ctx[tt][1]=0.f; ctx[tt][2]=0.f; ctx[tt][3]=0.f; }
#pragma unroll
    for (int r = 0; r < 4; ++r) { mrow[r] = NEG_BIG; lrow[r] = 0.f; }

    for (int k0 = 0; k0 < S_LEN; k0 += 64) {
        __syncthreads();   // prev PV reads done before restaging
        // stage K [key][d] -> bf16
#pragma unroll
        for (int i = 0; i < 4; ++i) {
            int fl  = t + 256 * i;
            int row = fl >> 4;
            int d4  = (fl & 15) << 2;
            float4 f = *(const float4*)(kp + ((size_t)bh * S_LEN + k0 + row) * HD + d4);
            bf16x4 vv;
            vv[0] = (bf16)f.x; vv[1] = (bf16)f.y; vv[2] = (bf16)f.z; vv[3] = (bf16)f.w;
            *(bf16x4*)&Kbf[row * 72 + d4] = vv;
        }
        // stage V^T [d][key] -> bf16 (vpT already transposed in global)
#pragma unroll
        for (int i = 0; i < 4; ++i) {
            int fl = t + 256 * i;
            int dl = fl >> 4;
            int k4 = (fl & 15) << 2;
            float4 f = *(const float4*)(vpT + ((size_t)bh * HD + dl) * S_LEN + k0 + k4);
            bf16x4 vv;
            vv[0] = (bf16)f.x; vv[1] = (bf16)f.y; vv[2] = (bf16)f.z; vv[3] = (bf16)f.w;
            *(bf16x4*)&VsT[dl * 72 + k4] = vv;
        }
        __syncthreads();

        // QK^T: 4 key tiles x 2 k-steps
        floatx4 sc[4];
#pragma unroll
        for (int tt = 0; tt < 4; ++tt) { sc[tt][0]=0.f; sc[tt][1]=0.f; sc[tt][2]=0.f; sc[tt][3]=0.f; }
#pragma unroll
        for (int st = 0; st < 2; ++st)
#pragma unroll
            for (int tt = 0; tt < 4; ++tt) {
                bf16x8 kf = *(const bf16x8*)&Kbf[(16 * tt + m) * 72 + 8 * quad + 32 * st];
                sc[tt] = __builtin_amdgcn_mfma_f32_16x16x32_bf16(qf[st], kf, sc[tt], 0, 0, 0);
            }

        // bias + mask + online softmax (rows 4*quad+r, in-register)
        float alpha[4];
#pragma unroll
        for (int r = 0; r < 4; ++r) {
            int grow = q0 + 16 * w + 4 * quad + r;
            const float* brow = bias + ((size_t)h * S_LEN + grow) * S_LEN + k0 + m;
            float s[4];
#pragma unroll
            for (int tt = 0; tt < 4; ++tt) {
                float v = sc[tt][r] + brow[16 * tt];
                size_t mi = (size_t)grow * S_LEN + k0 + 16 * tt + m;
                bool keep;
                if (flag == 0)      keep = ((const int*)mask)[mi] != 0;
                else if (flag == 1) keep = ((const unsigned char*)mask)[mi] != 0;
                else                keep = ((const float*)mask)[mi] != 0.f;
                s[tt] = keep ? v : NEG_BIG;
            }
            float mx = fmaxf(fmaxf(s[0], s[1]), fmaxf(s[2], s[3]));
            mx = fmaxf(mx, __shfl_xor(mx, 1));
            mx = fmaxf(mx, __shfl_xor(mx, 2));
            mx = fmaxf(mx, __shfl_xor(mx, 4));
            mx = fmaxf(mx, __shfl_xor(mx, 8));
            float mnew = fmaxf(mrow[r], mx);
            float al = __expf(mrow[r] - mnew);   // both NEG_BIG -> exp(0)=1, l stays 0
            float ls = 0.f;
#pragma unroll
            for (int tt = 0; tt < 4; ++tt) {
                float p = (s[tt] <= -1e37f) ? 0.f : __expf(s[tt] - mnew);
                ls += p;
                // wave-private strip: rows 16*w .. 16*w+15  (FIX: was missing 16*w)
                Pbf[(16 * w + 4 * quad + r) * 72 + 16 * tt + m] = (bf16)p;
            }
            ls += __shfl_xor(ls, 1);
            ls += __shfl_xor(ls, 2);
            ls += __shfl_xor(ls, 4);
            ls += __shfl_xor(ls, 8);
            lrow[r] = lrow[r] * al + ls;
            mrow[r] = mnew;
            alpha[r] = al;
        }
        // rescale accumulators
#pragma unroll
        for (int tt = 0; tt < 4; ++tt)
#pragma unroll
            for (int r = 0; r < 4; ++r) ctx[tt][r] *= alpha[r];

        // PV: Pbf rows 16w..16w+15 are wave-private (written by this wave),
        // VsT was synced after staging -> no extra barrier needed.
#pragma unroll
        for (int st = 0; st < 2; ++st) {
            bf16x8 pf = *(const bf16x8*)&Pbf[(16 * w + m) * 72 + 8 * quad + 32 * st];
#pragma unroll
            for (int tt = 0; tt < 4; ++tt) {
                bf16x8 vf = *(const bf16x8*)&VsT[(16 * tt + m) * 72 + 8 * quad + 32 * st];
                ctx[tt] = __builtin_amdgcn_mfma_f32_16x16x32_bf16(pf, vf, ctx[tt], 0, 0, 0);
            }
        }
    }

    // epilogue: ctx / l -> ctx_buf [b, s, h*64+d]
#pragma unroll
    for (int r = 0; r < 4; ++r) {
        float inv = lrow[r] > 0.f ? 1.f / lrow[r] : 0.f;
        int grow = q0 + 16 * w + 4 * quad + r;
#pragma unroll
        for (int tt = 0; tt < 4; ++tt) {
            ctxb[((size_t)b * S_LEN + grow) * CH + h * HD + 16 * tt + m] =
                ctx[tt][r] * inv;
        }
    }
}

extern "C" void kernel_launch(void* const* d_in, const int* in_sizes, int n_in,
                              void* d_out, int out_size, void* d_ws, size_t ws_size,
                              hipStream_t stream) {
    const float* k_in = (const float*)d_in[0];
    const float* v_in = (const float*)d_in[1];
    const float* q_in = (const float*)d_in[2];
    const void*  mask = d_in[3];
    const float* bias = (const float*)d_in[4];
    const float* Wq = (const float*)d_in[5];
    const float* bq = (const float*)d_in[6];
    const float* Wk = (const float*)d_in[7];
    const float* bk = (const float*)d_in[8];
    const float* Wv = (const float*)d_in[9];
    const float* bv = (const float*)d_in[10];
    const float* Wo = (const float*)d_in[11];
    const float* bo = (const float*)d_in[12];
    float* out = (float*)d_out;

    float* wsf  = (float*)d_ws;
    float* qp   = wsf;                 // [B,H,S,D]  8 MB
    float* kp   = wsf + 2097152;       // [B,H,S,D]  8 MB
    float* vpT  = wsf + 4194304;       // [B,H,D,S]  8 MB
    float* ctx  = wsf + 6291456;       // [B,S,CH]   8 MB
    int*   flag = (int*)(wsf + 8388608);

    detect_mask_kernel<<<1, 256, 0, stream>>>((const unsigned char*)mask, flag);
    qkv_gemm_kernel<<<dim3(4, 32, 3), 256, 0, stream>>>(
        q_in, k_in, v_in, Wq, bq, Wk, bk, Wv, bv, qp, kp, vpT);
    attn_kernel<<<dim3(32, 8, 2), 256, 0, stream>>>(
        qp, kp, vpT, bias, mask, flag, ctx);
    out_gemm_kernel<<<dim3(4, 32, 1), 256, 0, stream>>>(ctx, Wo, bo, out);
}

// Round 3
// 385.724 us; speedup vs baseline: 1.6239x; 1.6239x over previous
//
#include <hip/hip_runtime.h>
#include <hip/hip_bf16.h>

#define S_LEN 2048
#define NH 8
#define HD 64
#define CH 512
#define NEG_BIG (-3.0e38f)

typedef __bf16 bf16;
typedef bf16 bf16x8 __attribute__((ext_vector_type(8)));
typedef bf16 bf16x4 __attribute__((ext_vector_type(4)));
typedef float floatx4 __attribute__((ext_vector_type(4)));

// ---------------------------------------------------------------------------
// Mask dtype detection: bool mask may arrive as int32 / uint8 / float32.
// flag: 0=int32, 1=uint8, 2=float32.  (0 and 2 are both handled as
// "4-byte word nonzero"; only uint8 needs byte unpack.)
// ---------------------------------------------------------------------------
__global__ void detect_mask_kernel(const unsigned char* __restrict__ mb,
                                   int* __restrict__ flag_out) {
    __shared__ int s1, s3;
    if (threadIdx.x == 0) { s1 = 0; s3 = 0; }
    __syncthreads();
    int any1 = 0, any3 = 0;
    int base = threadIdx.x * 16;
    for (int i = base; i < base + 16; ++i) {
        unsigned char bch = mb[i];
        int m = i & 3;
        if (bch != 0) {
            if (m == 1) any1 = 1;
            if (m == 2 || m == 3) any3 = 1;
        }
    }
    if (any1) atomicOr(&s1, 1);
    if (any3) atomicOr(&s3, 1);
    __syncthreads();
    if (threadIdx.x == 0) {
        int f = 0;
        if (s1) f = 1;
        else if (s3) f = 2;
        *flag_out = f;
    }
}

// ---------------------------------------------------------------------------
// Weight prep: W [K=512][N=512] fp32 -> WT_hi/WT_lo bf16 [N][K] (transposed,
// hi/lo split: x = hi + lo, |x-hi-lo| <~ 2^-18 |x|). mats: 0=Wq 1=Wk 2=Wv 3=Wo
// ---------------------------------------------------------------------------
__global__ __launch_bounds__(256) void prep_weights_kernel(
    const float* __restrict__ Wq, const float* __restrict__ Wk,
    const float* __restrict__ Wv, const float* __restrict__ Wo,
    bf16* __restrict__ WThi, bf16* __restrict__ WTlo)
{
    __shared__ float tile[64][65];
    const int t = threadIdx.x;
    const int n0 = blockIdx.x * 64;
    const int k0 = blockIdx.y * 64;
    const int mat = blockIdx.z;
    const float* W = (mat == 0) ? Wq : (mat == 1) ? Wk : (mat == 2) ? Wv : Wo;
    bf16* hi = WThi + (size_t)mat * (CH * CH);
    bf16* lo = WTlo + (size_t)mat * (CH * CH);
#pragma unroll
    for (int i = 0; i < 4; ++i) {
        int row = (t >> 4) + 16 * i;
        int c4 = (t & 15) << 2;
        float4 f = *(const float4*)(W + (size_t)(k0 + row) * CH + n0 + c4);
        tile[row][c4 + 0] = f.x; tile[row][c4 + 1] = f.y;
        tile[row][c4 + 2] = f.z; tile[row][c4 + 3] = f.w;
    }
    __syncthreads();
#pragma unroll
    for (int i = 0; i < 4; ++i) {
        int nr = (t >> 4) + 16 * i;
        int k4 = (t & 15) << 2;
        bf16x4 h, l;
#pragma unroll
        for (int j = 0; j < 4; ++j) {
            float x = tile[k4 + j][nr];
            bf16 hv = (bf16)x;
            h[j] = hv;
            l[j] = (bf16)(x - (float)hv);
        }
        *(bf16x4*)(hi + (size_t)(n0 + nr) * CH + k0 + k4) = h;
        *(bf16x4*)(lo + (size_t)(n0 + nr) * CH + k0 + k4) = l;
    }
}

// ---------------------------------------------------------------------------
// bf16-MFMA GEMM with hi/lo split (fp32-equivalent accuracy).
// OUT[row,col] = (sum_k IN[row,k]*W[k,col] + BI[col]) * scale
// M=4096, N=512, K=512. 128x128 tile, BK=32, 256 thr = 4 waves; wave w owns
// rows [32w,32w+32). Frag maps (HW-verified): A[m=lane&15][k=quad*8+j],
// B[k=quad*8+j][n=lane&15] (read from WT[n][k] rows), C row=4*quad+reg,
// col=lane&15. LDS stride 40 shorts (80 B) keeps b128 16B-aligned.
// mode 0: OUT [b,h,s,d]; mode 1: OUT [b,h,d,s]; mode 2: flat [row,col].
// ---------------------------------------------------------------------------
__device__ __forceinline__ void gemm_bf16_tile(
    bf16* __restrict__ As_hi, bf16* __restrict__ As_lo,
    bf16* __restrict__ Bs_hi, bf16* __restrict__ Bs_lo,
    const float* __restrict__ IN, const bf16* __restrict__ WThi,
    const bf16* __restrict__ WTlo, const float* __restrict__ BI,
    float* __restrict__ OUT, float scale, int mode)
{
    const int t = threadIdx.x;
    const int w = t >> 6;
    const int lane = t & 63;
    const int m16 = lane & 15;
    const int quad = lane >> 4;
    const int m0 = blockIdx.y * 128;
    const int n0 = blockIdx.x * 128;

    const int arow = t >> 1;           // 0..127
    const int akc  = (t & 1) << 4;     // 0 or 16

    floatx4 acc[2][8];
#pragma unroll
    for (int mi = 0; mi < 2; ++mi)
#pragma unroll
        for (int ni = 0; ni < 8; ++ni) {
            acc[mi][ni][0] = 0.f; acc[mi][ni][1] = 0.f;
            acc[mi][ni][2] = 0.f; acc[mi][ni][3] = 0.f;
        }

    float4 af[4];
    bf16x8 pbh[2], pbl[2];

    auto loadA = [&](int k0) {
        const float* p = IN + (size_t)(m0 + arow) * CH + k0 + akc;
        af[0] = ((const float4*)p)[0];
        af[1] = ((const float4*)p)[1];
        af[2] = ((const float4*)p)[2];
        af[3] = ((const float4*)p)[3];
    };
    auto loadB = [&](int k0) {
        const bf16* ph = WThi + (size_t)(n0 + arow) * CH + k0 + akc;
        const bf16* pl = WTlo + (size_t)(n0 + arow) * CH + k0 + akc;
        pbh[0] = ((const bf16x8*)ph)[0]; pbh[1] = ((const bf16x8*)ph)[1];
        pbl[0] = ((const bf16x8*)pl)[0]; pbl[1] = ((const bf16x8*)pl)[1];
    };
    auto stage = [&]() {
#pragma unroll
        for (int hh = 0; hh < 2; ++hh) {
            bf16x8 h, l;
#pragma unroll
            for (int j = 0; j < 8; ++j) {
                float x = ((const float*)&af[2 * hh])[j];
                bf16 hv = (bf16)x;
                h[j] = hv;
                l[j] = (bf16)(x - (float)hv);
            }
            *(bf16x8*)&As_hi[arow * 40 + akc + 8 * hh] = h;
            *(bf16x8*)&As_lo[arow * 40 + akc + 8 * hh] = l;
        }
        *(bf16x8*)&Bs_hi[arow * 40 + akc + 0] = pbh[0];
        *(bf16x8*)&Bs_hi[arow * 40 + akc + 8] = pbh[1];
        *(bf16x8*)&Bs_lo[arow * 40 + akc + 0] = pbl[0];
        *(bf16x8*)&Bs_lo[arow * 40 + akc + 8] = pbl[1];
    };

    loadA(0); loadB(0);
    for (int ks = 0; ks < CH / 32; ++ks) {
        __syncthreads();
        stage();
        __syncthreads();
        if (ks + 1 < CH / 32) { loadA(32 * (ks + 1)); loadB(32 * (ks + 1)); }

        bf16x8 bh[8], bl[8];
#pragma unroll
        for (int ni = 0; ni < 8; ++ni) {
            bh[ni] = *(const bf16x8*)&Bs_hi[(16 * ni + m16) * 40 + 8 * quad];
            bl[ni] = *(const bf16x8*)&Bs_lo[(16 * ni + m16) * 40 + 8 * quad];
        }
#pragma unroll
        for (int mi = 0; mi < 2; ++mi) {
            bf16x8 ah = *(const bf16x8*)&As_hi[(32 * w + 16 * mi + m16) * 40 + 8 * quad];
            bf16x8 al = *(const bf16x8*)&As_lo[(32 * w + 16 * mi + m16) * 40 + 8 * quad];
#pragma unroll
            for (int ni = 0; ni < 8; ++ni) {
                acc[mi][ni] = __builtin_amdgcn_mfma_f32_16x16x32_bf16(ah, bh[ni], acc[mi][ni], 0, 0, 0);
                acc[mi][ni] = __builtin_amdgcn_mfma_f32_16x16x32_bf16(ah, bl[ni], acc[mi][ni], 0, 0, 0);
                acc[mi][ni] = __builtin_amdgcn_mfma_f32_16x16x32_bf16(al, bh[ni], acc[mi][ni], 0, 0, 0);
            }
        }
    }

#pragma unroll
    for (int mi = 0; mi < 2; ++mi) {
#pragma unroll
        for (int r = 0; r < 4; ++r) {
            int row = m0 + 32 * w + 16 * mi + 4 * quad + r;
            int bb = row >> 11;
            int ss = row & (S_LEN - 1);
#pragma unroll
            for (int ni = 0; ni < 8; ++ni) {
                int col = n0 + 16 * ni + m16;
                float v = (acc[mi][ni][r] + BI[col]) * scale;
                if (mode == 0) {
                    int hh = col >> 6, dd = col & 63;
                    OUT[(((size_t)bb * NH + hh) * S_LEN + ss) * HD + dd] = v;
                } else if (mode == 1) {
                    int hh = col >> 6, dd = col & 63;
                    OUT[(((size_t)bb * NH + hh) * HD + dd) * S_LEN + ss] = v;
                } else {
                    OUT[(size_t)row * CH + col] = v;
                }
            }
        }
    }
}

__global__ __launch_bounds__(256, 2) void qkv_gemm_kernel(
    const float* __restrict__ q_in, const float* __restrict__ k_in,
    const float* __restrict__ v_in,
    const bf16* __restrict__ WThi, const bf16* __restrict__ WTlo,
    const float* __restrict__ bq, const float* __restrict__ bk,
    const float* __restrict__ bv,
    float* __restrict__ qp, float* __restrict__ kp, float* __restrict__ vpT)
{
    __shared__ __attribute__((aligned(16))) bf16 As_hi[128 * 40];
    __shared__ __attribute__((aligned(16))) bf16 As_lo[128 * 40];
    __shared__ __attribute__((aligned(16))) bf16 Bs_hi[128 * 40];
    __shared__ __attribute__((aligned(16))) bf16 Bs_lo[128 * 40];
    int z = blockIdx.z;
    if (z == 0)
        gemm_bf16_tile(As_hi, As_lo, Bs_hi, Bs_lo, q_in,
                       WThi, WTlo, bq, qp, 0.125f, 0);
    else if (z == 1)
        gemm_bf16_tile(As_hi, As_lo, Bs_hi, Bs_lo, k_in,
                       WThi + (size_t)CH * CH, WTlo + (size_t)CH * CH, bk, kp, 1.0f, 0);
    else
        gemm_bf16_tile(As_hi, As_lo, Bs_hi, Bs_lo, v_in,
                       WThi + (size_t)2 * CH * CH, WTlo + (size_t)2 * CH * CH, bv, vpT, 1.0f, 1);
}

__global__ __launch_bounds__(256, 2) void out_gemm_kernel(
    const float* __restrict__ ctx,
    const bf16* __restrict__ WThi, const bf16* __restrict__ WTlo,
    const float* __restrict__ bo, float* __restrict__ out)
{
    __shared__ __attribute__((aligned(16))) bf16 As_hi[128 * 40];
    __shared__ __attribute__((aligned(16))) bf16 As_lo[128 * 40];
    __shared__ __attribute__((aligned(16))) bf16 Bs_hi[128 * 40];
    __shared__ __attribute__((aligned(16))) bf16 Bs_lo[128 * 40];
    gemm_bf16_tile(As_hi, As_lo, Bs_hi, Bs_lo, ctx,
                   WThi + (size_t)3 * CH * CH, WTlo + (size_t)3 * CH * CH, bo, out, 1.0f, 2);
}

// ---------------------------------------------------------------------------
// Flash attention v2: register-prefetched pipeline.
// Per k-tile: prefetch next tile's K/V/bias/mask (float4/uint4) into regs
// while computing current tile from LDS. Mask folded into bias at staging
// (sbias = keep ? bias : NEG_BIG, fp32 LDS) -> softmax inner loop has zero
// global loads / branches. LDS: Kbf/VsT/Pbf stride-72 bf16, sbias stride-68
// fp32 (both keep 16B alignment for vector ops; 2-way bank aliasing = free).
// ---------------------------------------------------------------------------
__global__ __launch_bounds__(256, 2) void attn_kernel(
    const float* __restrict__ qp, const float* __restrict__ kp,
    const float* __restrict__ vpT, const float* __restrict__ bias,
    const void* __restrict__ mask, const int* __restrict__ flagp,
    float* __restrict__ ctxb)
{
    __shared__ __attribute__((aligned(16))) bf16 Kbf[64 * 72];
    __shared__ __attribute__((aligned(16))) bf16 VsT[64 * 72];
    __shared__ __attribute__((aligned(16))) bf16 Pbf[64 * 72];
    __shared__ __attribute__((aligned(16))) float sbias[64 * 68];

    const int t    = threadIdx.x;
    const int w    = t >> 6;
    const int lane = t & 63;
    const int m    = lane & 15;
    const int quad = lane >> 4;
    const int q0   = blockIdx.x * 64;
    const int h    = blockIdx.y;
    const int b    = blockIdx.z;
    const int bh   = b * NH + h;
    const int flag = *flagp;

    // Q fragments: rows q0 + 16*w + m (prescaled by 1/8 in projection)
    bf16x8 qf[2];
    {
        const float* qrow =
            qp + ((size_t)bh * S_LEN + q0 + 16 * w + m) * HD + 8 * quad;
#pragma unroll
        for (int c = 0; c < 2; ++c) {
            float4 f0 = *(const float4*)(qrow + 32 * c);
            float4 f1 = *(const float4*)(qrow + 32 * c + 4);
            bf16x8 v;
            v[0] = (bf16)f0.x; v[1] = (bf16)f0.y; v[2] = (bf16)f0.z; v[3] = (bf16)f0.w;
            v[4] = (bf16)f1.x; v[5] = (bf16)f1.y; v[6] = (bf16)f1.z; v[7] = (bf16)f1.w;
            qf[c] = v;
        }
    }

    floatx4 ctx[4];
    float mrow[4], lrow[4];
#pragma unroll
    for (int tt = 0; tt < 4; ++tt) { ctx[tt][0]=0.f; ctx[tt][1]=0.f; ctx[tt][2]=0.f; ctx[tt][3]=0.f; }
#pragma unroll
    for (int r = 0; r < 4; ++r) { mrow[r] = NEG_BIG; lrow[r] = 0.f; }

    float4 kreg[4], vreg[4], breg[4];
    uint4  mreg[4];

    auto prefetch = [&](int k0) {
#pragma unroll
        for (int i = 0; i < 4; ++i) {
            int fl  = t + 256 * i;
            int row = fl >> 4;
            int c4  = (fl & 15) << 2;
            kreg[i] = *(const float4*)(kp  + ((size_t)bh * S_LEN + k0 + row) * HD + c4);
            vreg[i] = *(const float4*)(vpT + ((size_t)bh * HD + row) * S_LEN + k0 + c4);
            int grow = q0 + row;
            breg[i] = *(const float4*)(bias + ((size_t)h * S_LEN + grow) * S_LEN + k0 + c4);
            size_t mi0 = (size_t)grow * S_LEN + k0 + c4;
            if (flag == 1)
                mreg[i].x = *(const unsigned int*)((const unsigned char*)mask + mi0);
            else
                mreg[i] = *(const uint4*)((const unsigned int*)mask + mi0);
        }
    };
    auto stage = [&]() {
#pragma unroll
        for (int i = 0; i < 4; ++i) {
            int fl  = t + 256 * i;
            int row = fl >> 4;
            int c4  = (fl & 15) << 2;
            float4 kf = kreg[i], vf = vreg[i], bf = breg[i];
            bf16x4 kv, vv;
            kv[0] = (bf16)kf.x; kv[1] = (bf16)kf.y; kv[2] = (bf16)kf.z; kv[3] = (bf16)kf.w;
            vv[0] = (bf16)vf.x; vv[1] = (bf16)vf.y; vv[2] = (bf16)vf.z; vv[3] = (bf16)vf.w;
            *(bf16x4*)&Kbf[row * 72 + c4] = kv;
            *(bf16x4*)&VsT[row * 72 + c4] = vv;
            unsigned mj0, mj1, mj2, mj3;
            if (flag == 1) {
                unsigned mx = mreg[i].x;
                mj0 = mx & 255u; mj1 = (mx >> 8) & 255u;
                mj2 = (mx >> 16) & 255u; mj3 = mx >> 24;
            } else {
                mj0 = mreg[i].x; mj1 = mreg[i].y; mj2 = mreg[i].z; mj3 = mreg[i].w;
            }
            float4 sb;
            sb.x = mj0 ? bf.x : NEG_BIG;
            sb.y = mj1 ? bf.y : NEG_BIG;
            sb.z = mj2 ? bf.z : NEG_BIG;
            sb.w = mj3 ? bf.w : NEG_BIG;
            *(float4*)&sbias[row * 68 + c4] = sb;
        }
    };

    prefetch(0);
    for (int k0 = 0; k0 < S_LEN; k0 += 64) {
        __syncthreads();   // prev iter's LDS reads done before restage
        stage();
        __syncthreads();
        if (k0 + 64 < S_LEN) prefetch(k0 + 64);   // hide next tile's HBM latency

        // QK^T
        floatx4 sc[4];
#pragma unroll
        for (int tt = 0; tt < 4; ++tt) { sc[tt][0]=0.f; sc[tt][1]=0.f; sc[tt][2]=0.f; sc[tt][3]=0.f; }
#pragma unroll
        for (int st = 0; st < 2; ++st)
#pragma unroll
            for (int tt = 0; tt < 4; ++tt) {
                bf16x8 kf = *(const bf16x8*)&Kbf[(16 * tt + m) * 72 + 8 * quad + 32 * st];
                sc[tt] = __builtin_amdgcn_mfma_f32_16x16x32_bf16(qf[st], kf, sc[tt], 0, 0, 0);
            }

        // online softmax (masked bias from LDS; no globals, no branches)
        float alpha[4];
#pragma unroll
        for (int r = 0; r < 4; ++r) {
            int lrowq = 16 * w + 4 * quad + r;   // row within 64-row tile
            float s[4];
#pragma unroll
            for (int tt = 0; tt < 4; ++tt)
                s[tt] = sc[tt][r] + sbias[lrowq * 68 + 16 * tt + m];
            float mx = fmaxf(fmaxf(s[0], s[1]), fmaxf(s[2], s[3]));
            mx = fmaxf(mx, __shfl_xor(mx, 1));
            mx = fmaxf(mx, __shfl_xor(mx, 2));
            mx = fmaxf(mx, __shfl_xor(mx, 4));
            mx = fmaxf(mx, __shfl_xor(mx, 8));
            float mnew = fmaxf(mrow[r], mx);
            float al = __expf(mrow[r] - mnew);
            float ls = 0.f;
#pragma unroll
            for (int tt = 0; tt < 4; ++tt) {
                float p = (s[tt] <= -1e37f) ? 0.f : __expf(s[tt] - mnew);
                ls += p;
                Pbf[lrowq * 72 + 16 * tt + m] = (bf16)p;
            }
            ls += __shfl_xor(ls, 1);
            ls += __shfl_xor(ls, 2);
            ls += __shfl_xor(ls, 4);
            ls += __shfl_xor(ls, 8);
            lrow[r] = lrow[r] * al + ls;
            mrow[r] = mnew;
            alpha[r] = al;
        }
#pragma unroll
        for (int tt = 0; tt < 4; ++tt)
#pragma unroll
            for (int r = 0; r < 4; ++r) ctx[tt][r] *= alpha[r];

        // PV (Pbf rows 16w..16w+15 wave-private; VsT stable since stage sync)
#pragma unroll
        for (int st = 0; st < 2; ++st) {
            bf16x8 pf = *(const bf16x8*)&Pbf[(16 * w + m) * 72 + 8 * quad + 32 * st];
#pragma unroll
            for (int tt = 0; tt < 4; ++tt) {
                bf16x8 vf = *(const bf16x8*)&VsT[(16 * tt + m) * 72 + 8 * quad + 32 * st];
                ctx[tt] = __builtin_amdgcn_mfma_f32_16x16x32_bf16(pf, vf, ctx[tt], 0, 0, 0);
            }
        }
    }

    // epilogue: ctx / l -> ctx_buf [b, s, h*64+d]
#pragma unroll
    for (int r = 0; r < 4; ++r) {
        float inv = lrow[r] > 0.f ? 1.f / lrow[r] : 0.f;
        int grow = q0 + 16 * w + 4 * quad + r;
#pragma unroll
        for (int tt = 0; tt < 4; ++tt) {
            ctxb[((size_t)b * S_LEN + grow) * CH + h * HD + 16 * tt + m] =
                ctx[tt][r] * inv;
        }
    }
}

extern "C" void kernel_launch(void* const* d_in, const int* in_sizes, int n_in,
                              void* d_out, int out_size, void* d_ws, size_t ws_size,
                              hipStream_t stream) {
    const float* k_in = (const float*)d_in[0];
    const float* v_in = (const float*)d_in[1];
    const float* q_in = (const float*)d_in[2];
    const void*  mask = d_in[3];
    const float* bias = (const float*)d_in[4];
    const float* Wq = (const float*)d_in[5];
    const float* bq = (const float*)d_in[6];
    const float* Wk = (const float*)d_in[7];
    const float* bk = (const float*)d_in[8];
    const float* Wv = (const float*)d_in[9];
    const float* bv = (const float*)d_in[10];
    const float* Wo = (const float*)d_in[11];
    const float* bo = (const float*)d_in[12];
    float* out = (float*)d_out;

    float* wsf = (float*)d_ws;
    float* qp  = wsf;                   // [B,H,S,D]  8 MB
    float* kp  = wsf + 2097152;         // [B,H,S,D]  8 MB
    float* vpT = wsf + 4194304;         // [B,H,D,S]  8 MB
    float* ctx = wsf + 6291456;         // [B,S,CH]   8 MB
    bf16* WThi = (bf16*)(wsf + 8388608);     // 4 mats x 512x512 bf16 = 2 MB
    bf16* WTlo = WThi + (size_t)4 * CH * CH; // 2 MB
    int*  flag = (int*)(WTlo + (size_t)4 * CH * CH);

    detect_mask_kernel<<<1, 256, 0, stream>>>((const unsigned char*)mask, flag);
    prep_weights_kernel<<<dim3(8, 8, 4), 256, 0, stream>>>(
        Wq, Wk, Wv, Wo, WThi, WTlo);
    qkv_gemm_kernel<<<dim3(4, 32, 3), 256, 0, stream>>>(
        q_in, k_in, v_in, WThi, WTlo, bq, bk, bv, qp, kp, vpT);
    attn_kernel<<<dim3(32, 8, 2), 256, 0, stream>>>(
        qp, kp, vpT, bias, mask, flag, ctx);
    out_gemm_kernel<<<dim3(4, 32, 1), 256, 0, stream>>>(
        ctx, WThi, WTlo, bo, out);
}